// Round 3
// baseline (245.832 us; speedup 1.0000x reference)
//
#include <hip/hip_runtime.h>
#include <hip/hip_bf16.h>
#include <stdint.h>

typedef __bf16 bf16;
typedef __attribute__((ext_vector_type(8))) __bf16 bf16x8;
typedef __attribute__((ext_vector_type(4))) float f32x4;

#define DEVI __device__ __forceinline__

constexpr int Bz = 4, Sz = 2048, Dz = 512, Hz = 8, DKz = 64, DFFz = 2048;
constexpr int ROWSz = Bz * Sz;  // 8192
constexpr float EPSf = 1e-5f;
constexpr float C2f = 0.125f * 1.44269504088896f;  // 1/sqrt(DK) * log2(e)

// ---- async global->LDS, 16B per lane. LDS dest is wave-uniform base + lane*16.
DEVI void load_lds16(void* lds, const void* g) {
  __builtin_amdgcn_global_load_lds(
      (const __attribute__((address_space(1))) void*)(uintptr_t)(g),
      (__attribute__((address_space(3))) void*)(uint32_t)(uintptr_t)(lds),
      16, 0, 0);
}

// gfx950 cross-lane half-swaps (pure VALU; all lanes active in this kernel).
DEVI void permswap32(unsigned& x, unsigned& y) {
  asm("v_permlane32_swap_b32 %0, %1" : "+v"(x), "+v"(y));
}
DEVI void permswap16(unsigned& x, unsigned& y) {
  asm("v_permlane16_swap_b32 %0, %1" : "+v"(x), "+v"(y));
}

// =====================================================================
// GEMM (best measured mix, R11/R14):  C = A[M,K] @ Bt[N,K]^T  +bias.
// =====================================================================
template <int BM, int BK, int EPI>
__global__ __launch_bounds__(256, BM == 128 ? 4 : 3) void gemm_bt(
    const bf16* __restrict__ A, const bf16* __restrict__ Bt,
    const float* __restrict__ bias, const float* __restrict__ resid,
    const bf16* __restrict__ residb, bf16* __restrict__ aux,
    void* __restrict__ Cout, int M, int N, int K) {
  constexpr int BN = 128;
  constexpr int MI = BM / 32;          // m-frags per wave
  constexpr int RPI = 512 / BK;        // rows per 16B-issue (16 @BK32, 8 @BK64)
  constexpr int AISS = (BM / 4) / RPI; // A issues per wave
  constexpr int BISS = 32 / RPI;       // B issues per wave
  __shared__ alignas(16) bf16 sA[2][BM * BK];
  __shared__ alignas(16) bf16 sB[2][BN * BK];
  const int tid = threadIdx.x;
  const int lane = tid & 63;
  const int wv = tid >> 6;
  const int n0 = blockIdx.x * BN;
  const int m0 = blockIdx.y * BM;

  const int srow = (BK == 32) ? (lane >> 2) : (lane >> 3);
  const int sch = (BK == 32) ? (((lane & 3) ^ (srow & 3)) * 8)
                             : (((lane & 7) ^ (srow & 7)) * 8);
  const bf16* gA = A + (size_t)(m0 + wv * (BM / 4) + srow) * K + sch;
  const bf16* gB = Bt + (size_t)(n0 + wv * 32 + srow) * K + sch;

  const int wm = (wv >> 1) * (BM / 2);
  const int wn = (wv & 1) * 64;
  const int fr = lane & 15;
  const int fq = lane >> 4;

  auto stage = [&](int buf, int k0) {
#pragma unroll
    for (int j = 0; j < AISS; ++j)
      load_lds16(sA[buf] + (wv * (BM / 4) + j * RPI) * BK, gA + (size_t)(j * RPI) * K + k0);
#pragma unroll
    for (int j = 0; j < BISS; ++j)
      load_lds16(sB[buf] + (wv * 32 + j * RPI) * BK, gB + (size_t)(j * RPI) * K + k0);
  };

  f32x4 acc[MI][4] = {};

  stage(0, 0);
  __syncthreads();  // barrier's vmcnt(0) drain completes tile 0

  const int niter = K / BK;
  for (int it = 0; it < niter; ++it) {
    const int cur = it & 1;
    if (it + 1 < niter) stage(cur ^ 1, (it + 1) * BK);
#pragma unroll
    for (int kk = 0; kk < BK / 32; ++kk) {
      const int fc = (BK == 32) ? ((fq ^ (fr & 3)) * 8)
                                : (((4 * kk + fq) ^ (fr & 7)) * 8);
      bf16x8 af[MI], bfr[4];
#pragma unroll
      for (int i = 0; i < MI; ++i)
        af[i] = *(const bf16x8*)(sA[cur] + (wm + i * 16 + fr) * BK + fc);
#pragma unroll
      for (int j = 0; j < 4; ++j)
        bfr[j] = *(const bf16x8*)(sB[cur] + (wn + j * 16 + fr) * BK + fc);
#pragma unroll
      for (int i = 0; i < MI; ++i)
#pragma unroll
        for (int j = 0; j < 4; ++j)
          acc[i][j] = __builtin_amdgcn_mfma_f32_16x16x32_bf16(af[i], bfr[j], acc[i][j], 0, 0, 0);
    }
    __syncthreads();  // readers done with cur + prefetch DMA drained
  }

#pragma unroll
  for (int i = 0; i < MI; ++i) {
#pragma unroll
    for (int j = 0; j < 4; ++j) {
      const int col = n0 + wn + j * 16 + fr;
      const float bv = bias[col];
      if (EPI == 3 && col >= 1024) {
        const int row0 = m0 + wm + i * 16 + fq * 4;
        const int hh = (col - 1024) >> 6, dk = (col - 1024) & 63;
        const int bb = row0 >> 11, s0 = row0 & 2047;
        bf16 pv[4];
#pragma unroll
        for (int r = 0; r < 4; ++r) pv[r] = (bf16)(acc[i][j][r] + bv);
        *(uint2*)(aux + (size_t)((bb * 8 + hh) * 64 + dk) * 2048 + s0) = *(const uint2*)pv;
      } else {
#pragma unroll
        for (int r = 0; r < 4; ++r) {
          const int row = m0 + wm + i * 16 + fq * 4 + r;
          const size_t idx = (size_t)row * N + col;
          float v = acc[i][j][r] + bv;
          if (EPI == 1) {
            ((bf16*)Cout)[idx] = (bf16)(v + resid[idx]);
          } else if (EPI == 2) {
            ((bf16*)Cout)[idx] = (bf16)(v > 0.f ? v : 0.f);
          } else if (EPI == 3) {
            ((bf16*)Cout)[idx] = (bf16)(col < 512 ? v * C2f : v);
          } else {
            ((bf16*)Cout)[idx] = (bf16)(v + (float)residb[idx]);
          }
        }
      }
    }
  }
}

// =====================================================================
// Flash attention v4 (R3): occupancy-first re-tiling.
// R2 post-mortem: MfmaUtil pinned 25%, VALU 48%, stalls 27% with only
// 2 waves/SIMD (grid 512 = 2 blocks/CU, GRID-limited). Pipes can't
// overlap without TLP. Fix: 64 q-rows/block (16/wave), grid 1024 =
// 4 blocks/CU; LDS 32KB (2 K/V dbuf, Q staged in sV[1], own-rows only
// => barrier-free prologue); straight-line QKT->SM->PV per iter (TLP
// does the overlap now). bid%8 == head => each head's 32 blocks pinned
// to one XCD (K/V 512KB stays L2-resident; 4 heads/XCD = 2MB of 4MB).
// =====================================================================
__global__ __launch_bounds__(256, 4) void flash_attn(
    const bf16* __restrict__ qkv, const bf16* __restrict__ Vt,
    bf16* __restrict__ ctx) {
  const int bid = blockIdx.x;
  const int qt = bid >> 5;         // 0..31
  const int bh = bid & 31;         // bid%8 == h -> XCD pinning per head
  const int h = bh & 7;
  const int b = bh >> 3;
  const int q0 = qt * 64;
  const int tid = threadIdx.x, lane = tid & 63, wv = tid >> 6;
  const int fr = lane & 15, fq = lane >> 4;
  const int xsw = fr & 7;

  __shared__ alignas(16) bf16 sK[2][64 * 64];
  __shared__ alignas(16) bf16 sV[2][64 * 64];

  const int srow = lane >> 3;                // 0..7 within 8-row issue
  const int scol = ((lane & 7) ^ srow) * 8;  // swizzled chunk (elements)

  const bf16* gQ = qkv + (size_t)(b * Sz + q0 + wv * 16 + srow) * 1536 + h * 64 + scol;
  const bf16* gK = qkv + (size_t)(b * Sz + wv * 16 + srow) * 1536 + 512 + h * 64 + scol;
  const bf16* gV = Vt + (size_t)((b * 8 + h) * 64 + wv * 16 + srow) * Sz + scol;

  auto stage = [&](int buf, int t) {
    const size_t t0r = (size_t)t * 64;
    load_lds16(sK[buf] + (wv * 16 + 0) * 64, gK + t0r * 1536);
    load_lds16(sK[buf] + (wv * 16 + 8) * 64, gK + (t0r + 8) * 1536);
    load_lds16(sV[buf] + (wv * 16 + 0) * 64, gV + t0r);
    load_lds16(sV[buf] + (wv * 16 + 8) * 64, gV + (size_t)8 * Sz + t0r);
  };

  // ---- barrier-free prologue: Q staged into sV[1]; each wave stages and
  // reads ONLY its own 16 rows, so own-vmcnt/lgkm ordering suffices.
  bf16* sQ = (bf16*)sV[1];
  load_lds16(sQ + (wv * 16 + 0) * 64, gQ);
  load_lds16(sQ + (wv * 16 + 8) * 64, gQ + (size_t)8 * 1536);
  stage(0, 0);                                      // 4 loads
  asm volatile("s_waitcnt vmcnt(4)" ::: "memory");  // Q's 2 loads retired

  const int colc0 = (fq ^ xsw) * 8;
  const int colc1 = ((fq + 4) ^ xsw) * 8;
  int qsrc[4];
#pragma unroll
  for (int r = 0; r < 4; ++r) qsrc[r] = (fq * 4 + r) | (lane & 48);

  bf16x8 qb[2];
  qb[0] = *(const bf16x8*)(sQ + (wv * 16 + fr) * 64 + colc0);
  qb[1] = *(const bf16x8*)(sQ + (wv * 16 + fr) * 64 + colc1);
  asm volatile("s_waitcnt lgkmcnt(0)" ::: "memory");
  stage(1, 1);  // overwrites sV[1] = own Q rows only (already in regs)
  asm volatile("s_waitcnt vmcnt(4)" ::: "memory");  // stage(0) retired (own)
  __builtin_amdgcn_s_barrier();                     // tile 0 ready everywhere
  asm volatile("" ::: "memory");

  float l_part = 0.f;
  f32x4 acc_o[4] = {};

  for (int t = 0; t < 32; ++t) {
    const int cur = t & 1;
    if (t >= 1 && t + 1 < 32) stage(cur ^ 1, t + 1);

    // S^T = K Q^T : lane holds q=fr, t'=fq*4+r+16j
    bf16x8 kf[2][4];
#pragma unroll
    for (int j = 0; j < 4; ++j) {
      kf[0][j] = *(const bf16x8*)(sK[cur] + (j * 16 + fr) * 64 + colc0);
      kf[1][j] = *(const bf16x8*)(sK[cur] + (j * 16 + fr) * 64 + colc1);
    }
    f32x4 sc[4];
    __builtin_amdgcn_s_setprio(1);
#pragma unroll
    for (int j = 0; j < 4; ++j) {
      f32x4 z = {0.f, 0.f, 0.f, 0.f};
      z = __builtin_amdgcn_mfma_f32_16x16x32_bf16(kf[0][j], qb[0], z, 0, 0, 0);
      sc[j] = __builtin_amdgcn_mfma_f32_16x16x32_bf16(kf[1][j], qb[1], z, 0, 0, 0);
    }
    __builtin_amdgcn_s_setprio(0);

    // max-free softmax: e = exp2(sc); pack to bf16 pairs
    unsigned c0[4], c1[4];
    float rs = 0.f;
#pragma unroll
    for (int j = 0; j < 4; ++j) {
      float e0 = __builtin_amdgcn_exp2f(sc[j][0]);
      float e1 = __builtin_amdgcn_exp2f(sc[j][1]);
      float e2 = __builtin_amdgcn_exp2f(sc[j][2]);
      float e3 = __builtin_amdgcn_exp2f(sc[j][3]);
      rs += (e0 + e1) + (e2 + e3);
      union { bf16 hh[2]; unsigned u; } pka, pkb;
      pka.hh[0] = (bf16)e0; pka.hh[1] = (bf16)e1;  // fuses to v_cvt_pk_bf16_f32
      pkb.hh[0] = (bf16)e2; pkb.hh[1] = (bf16)e3;
      c0[j] = pka.u;
      c1[j] = pkb.u;
    }
    l_part += rs;

    // in-register P redistribution to PV A-frag layout (verified R1/R2)
    bf16x8 pa[2];
#pragma unroll
    for (int kk = 0; kk < 2; ++kk) {
      unsigned x0 = c0[2 * kk], y0 = c0[2 * kk + 1];
      permswap32(x0, y0);
      permswap16(x0, y0);
      unsigned x1 = c1[2 * kk], y1 = c1[2 * kk + 1];
      permswap32(x1, y1);
      permswap16(x1, y1);
      union { unsigned u[4]; bf16x8 v; } pk;
      pk.u[0] = x0; pk.u[1] = x1; pk.u[2] = y0; pk.u[3] = y1;
      pa[kk] = pk.v;
    }

    // O += P V
    bf16x8 vf[2][4];
#pragma unroll
    for (int j = 0; j < 4; ++j) {
      vf[0][j] = *(const bf16x8*)(sV[cur] + (j * 16 + fr) * 64 + colc0);
      vf[1][j] = *(const bf16x8*)(sV[cur] + (j * 16 + fr) * 64 + colc1);
    }
    __builtin_amdgcn_s_setprio(1);
#pragma unroll
    for (int kk = 0; kk < 2; ++kk)
#pragma unroll
      for (int j = 0; j < 4; ++j)
        acc_o[j] = __builtin_amdgcn_mfma_f32_16x16x32_bf16(pa[kk], vf[kk][j], acc_o[j], 0, 0, 0);
    __builtin_amdgcn_s_setprio(0);

    if (t + 1 < 32) {
      asm volatile("s_waitcnt vmcnt(0)" ::: "memory");  // stage(t+1) landed
      __builtin_amdgcn_s_barrier();
      asm volatile("" ::: "memory");
    }
  }

  float l = l_part;
  l += __shfl_xor(l, 16, 64);
  l += __shfl_xor(l, 32, 64);
  float rl[4];
#pragma unroll
  for (int r = 0; r < 4; ++r) rl[r] = 1.0f / __shfl(l, qsrc[r], 64);
#pragma unroll
  for (int j = 0; j < 4; ++j)
#pragma unroll
    for (int r = 0; r < 4; ++r) {
      const int row = b * Sz + q0 + wv * 16 + fq * 4 + r;
      const int col = h * 64 + j * 16 + fr;
      ctx[(size_t)row * Dz + col] = (bf16)(acc_o[j][r] * rl[r]);
    }
}

// =====================================================================
// LayerNorm: one wave per row of 512. bf16 input; fp32 or bf16 output.
// =====================================================================
template <int OUT_F32>
__global__ __launch_bounds__(256) void layer_norm_k(
    const bf16* __restrict__ y, const float* __restrict__ g,
    const float* __restrict__ be, void* __restrict__ out) {
  const int row = blockIdx.x * 4 + (threadIdx.x >> 6);
  const int lane = threadIdx.x & 63;
  const int col = lane * 8;
  bf16x8 hv = *(const bf16x8*)(y + (size_t)row * Dz + col);
  float v[8];
  float s = 0.f, ss = 0.f;
#pragma unroll
  for (int i = 0; i < 8; ++i) {
    v[i] = (float)hv[i];
    s += v[i];
    ss += v[i] * v[i];
  }
#pragma unroll
  for (int o = 1; o < 64; o <<= 1) {
    s += __shfl_xor(s, o, 64);
    ss += __shfl_xor(ss, o, 64);
  }
  const float mu = s * (1.0f / Dz);
  const float rstd = rsqrtf(ss * (1.0f / Dz) - mu * mu + EPSf);
  const float4* g4 = (const float4*)(g + col);
  const float4* b4 = (const float4*)(be + col);
  float4 ga = g4[0], gb = g4[1], ba = b4[0], bb = b4[1];
  float o8[8];
  o8[0] = (v[0] - mu) * rstd * ga.x + ba.x;
  o8[1] = (v[1] - mu) * rstd * ga.y + ba.y;
  o8[2] = (v[2] - mu) * rstd * ga.z + ba.z;
  o8[3] = (v[3] - mu) * rstd * ga.w + ba.w;
  o8[4] = (v[4] - mu) * rstd * gb.x + bb.x;
  o8[5] = (v[5] - mu) * rstd * gb.y + bb.y;
  o8[6] = (v[6] - mu) * rstd * gb.z + bb.z;
  o8[7] = (v[7] - mu) * rstd * gb.w + bb.w;
  if (OUT_F32) {
    float4* of = (float4*)((float*)out + (size_t)row * Dz + col);
    of[0] = make_float4(o8[0], o8[1], o8[2], o8[3]);
    of[1] = make_float4(o8[4], o8[5], o8[6], o8[7]);
  } else {
    bf16 ob[8];
#pragma unroll
    for (int i = 0; i < 8; ++i) ob[i] = (bf16)o8[i];
    *(uint4*)((bf16*)out + (size_t)row * Dz + col) = *(const uint4*)ob;
  }
}

// =====================================================================
// Fused prep: all 6 weight transposes (fp32[K,N] -> bf16[N,K], 64x64
// tiles), bias concat, x -> bf16 cast. One launch.
// =====================================================================
__global__ __launch_bounds__(256) void prep_all(
    const float* __restrict__ Wq, const float* __restrict__ Wk,
    const float* __restrict__ Wv, const float* __restrict__ Wo,
    const float* __restrict__ W1, const float* __restrict__ W2,
    const float* __restrict__ bq, const float* __restrict__ bk,
    const float* __restrict__ bv, const float* __restrict__ x,
    bf16* __restrict__ WqkvT, bf16* __restrict__ WoT,
    bf16* __restrict__ W1T, bf16* __restrict__ W2T,
    float* __restrict__ bqkv, bf16* __restrict__ xb) {
  __shared__ float tile[64][65];
  const int blk = blockIdx.x;
  const int t = threadIdx.x;
  if (blk < 768) {
    const float* W;
    bf16* Wt;
    int K, N, local;
    if (blk < 64)       { W = Wq; Wt = WqkvT;                       K = 512;  N = 512;  local = blk; }
    else if (blk < 128) { W = Wk; Wt = WqkvT + (size_t)512 * 512;   K = 512;  N = 512;  local = blk - 64; }
    else if (blk < 192) { W = Wv; Wt = WqkvT + (size_t)1024 * 512;  K = 512;  N = 512;  local = blk - 128; }
    else if (blk < 256) { W = Wo; Wt = WoT;                         K = 512;  N = 512;  local = blk - 192; }
    else if (blk < 512) { W = W1; Wt = W1T;                         K = 512;  N = 2048; local = blk - 256; }
    else                { W = W2; Wt = W2T;                         K = 2048; N = 512;  local = blk - 512; }
    const int kt = K / 64;
    const int k0 = (local % kt) * 64, n0 = (local / kt) * 64;
    const int r = t >> 2, c = (t & 3) * 16;
    const float* src = W + (size_t)(k0 + r) * N + n0 + c;
#pragma unroll
    for (int i = 0; i < 4; ++i) {
      float4 v = ((const float4*)src)[i];
      tile[r][c + i * 4 + 0] = v.x;
      tile[r][c + i * 4 + 1] = v.y;
      tile[r][c + i * 4 + 2] = v.z;
      tile[r][c + i * 4 + 3] = v.w;
    }
    __syncthreads();
    union { bf16 hh[16]; uint4 u[2]; } pk;
#pragma unroll
    for (int i = 0; i < 16; ++i) pk.hh[i] = (bf16)tile[c + i][r];
    uint4* dst = (uint4*)(Wt + (size_t)(n0 + r) * K + k0 + c);
    dst[0] = pk.u[0];
    dst[1] = pk.u[1];
  } else if (blk == 768) {
    for (int i = t; i < 1536; i += 256)
      bqkv[i] = i < 512 ? bq[i] : (i < 1024 ? bk[i - 512] : bv[i - 1024]);
  } else {
    const int local = blk - 769;  // 0..1023, each handles 1024 float4s
#pragma unroll
    for (int k = 0; k < 4; ++k) {
      const int i = local * 1024 + k * 256 + t;
      float4 v = ((const float4*)x)[i];
      bf16 tv[4] = {(bf16)v.x, (bf16)v.y, (bf16)v.z, (bf16)v.w};
      ((uint2*)xb)[i] = *(const uint2*)tv;
    }
  }
}

// =====================================================================
extern "C" void kernel_launch(void* const* d_in, const int* in_sizes, int n_in,
                              void* d_out, int out_size, void* d_ws, size_t ws_size,
                              hipStream_t stream) {
  const float* x   = (const float*)d_in[0];
  const float* Wq  = (const float*)d_in[1];
  const float* bq  = (const float*)d_in[2];
  const float* Wk  = (const float*)d_in[3];
  const float* bk  = (const float*)d_in[4];
  const float* Wv  = (const float*)d_in[5];
  const float* bvp = (const float*)d_in[6];
  const float* Wo  = (const float*)d_in[7];
  const float* bo  = (const float*)d_in[8];
  const float* W1  = (const float*)d_in[9];
  const float* b1  = (const float*)d_in[10];
  const float* W2  = (const float*)d_in[11];
  const float* b2  = (const float*)d_in[12];
  const float* g1  = (const float*)d_in[13];
  const float* be1 = (const float*)d_in[14];
  const float* g2  = (const float*)d_in[15];
  const float* be2 = (const float*)d_in[16];

  char* ws = (char*)d_ws;
  size_t off = 0;
  auto alloc = [&](size_t bytes) -> void* {
    void* p = ws + off;
    off += (bytes + 255) & ~(size_t)255;
    return p;
  };
  bf16*  WqkvT = (bf16*)alloc((size_t)1536 * 512 * 2);
  float* bqkv  = (float*)alloc(1536 * 4);
  bf16*  WoT   = (bf16*)alloc((size_t)512 * 512 * 2);
  bf16*  W1T   = (bf16*)alloc((size_t)2048 * 512 * 2);
  bf16*  W2T   = (bf16*)alloc((size_t)512 * 2048 * 2);
  bf16*  xb    = (bf16*)alloc((size_t)ROWSz * 512 * 2);
  bf16*  qkv   = (bf16*)alloc((size_t)ROWSz * 1536 * 2);    // 24 MB (Q,K rows)
  bf16*  Vt    = (bf16*)alloc((size_t)32 * 64 * 2048 * 2);  // 8 MB, written by QKV epilogue
  bf16*  ctx   = (bf16*)alloc((size_t)ROWSz * 512 * 2);
  bf16*  y1    = (bf16*)alloc((size_t)ROWSz * 512 * 2);     // Wo+resid out (bf16)
  bf16*  x1b   = (bf16*)alloc((size_t)ROWSz * 512 * 2);     // LN1 out
  bf16*  hbuf  = qkv;  // 32 MB alias over qkv+Vt (dead after attention+Wo)
  bf16*  y2    = y1;   // dead after LN1

  // fused prep (weights, bias concat, x cast)
  prep_all<<<dim3(1793), 256, 0, stream>>>(Wq, Wk, Wv, Wo, W1, W2, bq, bk, bvp, x,
                                           WqkvT, WoT, W1T, W2T, bqkv, xb);

  // QKV projection (fused N=1536; Q cols pre-scaled by C2; V cols -> Vt transposed)
  gemm_bt<128, 32, 3><<<dim3(12, 64), 256, 0, stream>>>(xb, WqkvT, bqkv, nullptr, nullptr, Vt, qkv, ROWSz, 1536, 512);
  // attention (4 blocks/CU: 1024 blocks x 64 q-rows, head-pinned XCD map)
  flash_attn<<<dim3(1024), 256, 0, stream>>>(qkv, Vt, ctx);
  // Wo + bias + residual(xb bf16) -> y1 bf16
  gemm_bt<64, 64, 4><<<dim3(4, 128), 256, 0, stream>>>(ctx, WoT, bo, nullptr, xb, nullptr, y1, ROWSz, 512, 512);
  layer_norm_k<0><<<dim3(2048), 256, 0, stream>>>(y1, g1, be1, x1b);
  // FFN
  gemm_bt<128, 32, 2><<<dim3(16, 64), 256, 0, stream>>>(x1b, W1T, b1, nullptr, nullptr, nullptr, hbuf, ROWSz, 2048, 512);
  gemm_bt<64, 64, 4><<<dim3(4, 128), 256, 0, stream>>>(hbuf, W2T, b2, nullptr, x1b, nullptr, y2, ROWSz, 512, 2048);
  layer_norm_k<1><<<dim3(2048), 256, 0, stream>>>(y2, g2, be2, d_out);
}

// Round 5
// 244.448 us; speedup vs baseline: 1.0057x; 1.0057x over previous
//
#include <hip/hip_runtime.h>
#include <hip/hip_bf16.h>
#include <stdint.h>

typedef __bf16 bf16;
typedef __attribute__((ext_vector_type(8))) __bf16 bf16x8;
typedef __attribute__((ext_vector_type(4))) float f32x4;

#define DEVI __device__ __forceinline__

constexpr int Bz = 4, Sz = 2048, Dz = 512, Hz = 8, DKz = 64, DFFz = 2048;
constexpr int ROWSz = Bz * Sz;  // 8192
constexpr float EPSf = 1e-5f;
constexpr float C2f = 0.125f * 1.44269504088896f;  // 1/sqrt(DK) * log2(e)

// ---- async global->LDS, 16B per lane. LDS dest is wave-uniform base + lane*16.
DEVI void load_lds16(void* lds, const void* g) {
  __builtin_amdgcn_global_load_lds(
      (const __attribute__((address_space(1))) void*)(uintptr_t)(g),
      (__attribute__((address_space(3))) void*)(uint32_t)(uintptr_t)(lds),
      16, 0, 0);
}

// gfx950 cross-lane half-swaps (pure VALU; all lanes active in this kernel).
DEVI void permswap32(unsigned& x, unsigned& y) {
  asm("v_permlane32_swap_b32 %0, %1" : "+v"(x), "+v"(y));
}
DEVI void permswap16(unsigned& x, unsigned& y) {
  asm("v_permlane16_swap_b32 %0, %1" : "+v"(x), "+v"(y));
}

// =====================================================================
// GEMM (best measured mix, R11/R14):  C = A[M,K] @ Bt[N,K]^T  +bias.
// =====================================================================
template <int BM, int BK, int EPI>
__global__ __launch_bounds__(256, BM == 128 ? 4 : 3) void gemm_bt(
    const bf16* __restrict__ A, const bf16* __restrict__ Bt,
    const float* __restrict__ bias, const float* __restrict__ resid,
    const bf16* __restrict__ residb, bf16* __restrict__ aux,
    void* __restrict__ Cout, int M, int N, int K) {
  constexpr int BN = 128;
  constexpr int MI = BM / 32;          // m-frags per wave
  constexpr int RPI = 512 / BK;        // rows per 16B-issue (16 @BK32, 8 @BK64)
  constexpr int AISS = (BM / 4) / RPI; // A issues per wave
  constexpr int BISS = 32 / RPI;       // B issues per wave
  __shared__ alignas(16) bf16 sA[2][BM * BK];
  __shared__ alignas(16) bf16 sB[2][BN * BK];
  const int tid = threadIdx.x;
  const int lane = tid & 63;
  const int wv = tid >> 6;
  const int n0 = blockIdx.x * BN;
  const int m0 = blockIdx.y * BM;

  const int srow = (BK == 32) ? (lane >> 2) : (lane >> 3);
  const int sch = (BK == 32) ? (((lane & 3) ^ (srow & 3)) * 8)
                             : (((lane & 7) ^ (srow & 7)) * 8);
  const bf16* gA = A + (size_t)(m0 + wv * (BM / 4) + srow) * K + sch;
  const bf16* gB = Bt + (size_t)(n0 + wv * 32 + srow) * K + sch;

  const int wm = (wv >> 1) * (BM / 2);
  const int wn = (wv & 1) * 64;
  const int fr = lane & 15;
  const int fq = lane >> 4;

  auto stage = [&](int buf, int k0) {
#pragma unroll
    for (int j = 0; j < AISS; ++j)
      load_lds16(sA[buf] + (wv * (BM / 4) + j * RPI) * BK, gA + (size_t)(j * RPI) * K + k0);
#pragma unroll
    for (int j = 0; j < BISS; ++j)
      load_lds16(sB[buf] + (wv * 32 + j * RPI) * BK, gB + (size_t)(j * RPI) * K + k0);
  };

  f32x4 acc[MI][4] = {};

  stage(0, 0);
  __syncthreads();  // barrier's vmcnt(0) drain completes tile 0

  const int niter = K / BK;
  for (int it = 0; it < niter; ++it) {
    const int cur = it & 1;
    if (it + 1 < niter) stage(cur ^ 1, (it + 1) * BK);
#pragma unroll
    for (int kk = 0; kk < BK / 32; ++kk) {
      const int fc = (BK == 32) ? ((fq ^ (fr & 3)) * 8)
                                : (((4 * kk + fq) ^ (fr & 7)) * 8);
      bf16x8 af[MI], bfr[4];
#pragma unroll
      for (int i = 0; i < MI; ++i)
        af[i] = *(const bf16x8*)(sA[cur] + (wm + i * 16 + fr) * BK + fc);
#pragma unroll
      for (int j = 0; j < 4; ++j)
        bfr[j] = *(const bf16x8*)(sB[cur] + (wn + j * 16 + fr) * BK + fc);
#pragma unroll
      for (int i = 0; i < MI; ++i)
#pragma unroll
        for (int j = 0; j < 4; ++j)
          acc[i][j] = __builtin_amdgcn_mfma_f32_16x16x32_bf16(af[i], bfr[j], acc[i][j], 0, 0, 0);
    }
    __syncthreads();  // readers done with cur + prefetch DMA drained
  }

#pragma unroll
  for (int i = 0; i < MI; ++i) {
#pragma unroll
    for (int j = 0; j < 4; ++j) {
      const int col = n0 + wn + j * 16 + fr;
      const float bv = bias[col];
      if (EPI == 3 && col >= 1024) {
        const int row0 = m0 + wm + i * 16 + fq * 4;
        const int hh = (col - 1024) >> 6, dk = (col - 1024) & 63;
        const int bb = row0 >> 11, s0 = row0 & 2047;
        bf16 pv[4];
#pragma unroll
        for (int r = 0; r < 4; ++r) pv[r] = (bf16)(acc[i][j][r] + bv);
        *(uint2*)(aux + (size_t)((bb * 8 + hh) * 64 + dk) * 2048 + s0) = *(const uint2*)pv;
      } else {
#pragma unroll
        for (int r = 0; r < 4; ++r) {
          const int row = m0 + wm + i * 16 + fq * 4 + r;
          const size_t idx = (size_t)row * N + col;
          float v = acc[i][j][r] + bv;
          if (EPI == 1) {
            ((bf16*)Cout)[idx] = (bf16)(v + resid[idx]);
          } else if (EPI == 2) {
            ((bf16*)Cout)[idx] = (bf16)(v > 0.f ? v : 0.f);
          } else if (EPI == 3) {
            ((bf16*)Cout)[idx] = (bf16)(col < 512 ? v * C2f : v);
          } else {
            ((bf16*)Cout)[idx] = (bf16)(v + (float)residb[idx]);
          }
        }
      }
    }
  }
}

// =====================================================================
// Flash attention v5 (R4/R5 resubmit): 8-wave blocks, 128 q-rows,
// 4 waves/SIMD. R3 post-mortem: XCD pinning worked (FETCH 70->12MB)
// but 64-row tile halved per-block amortization -> regression. Fix:
// 128 q-rows/block with 8 waves x 16 q-rows (HK shape). Grid 512 =
// 2 blocks/CU x 8 waves = 4 waves/SIMD. Per-wave per-iter staging =
// 2 DMA issues (K,V split 8 ways). Q direct global->VGPR (no LDS
// round-trip). 3-buffer K/V, counted vmcnt(2) keeps one stage in
// flight across barriers. Head-pinned XCD map (bid%8==h) kept.
// =====================================================================
__global__ __launch_bounds__(512, 4) void flash_attn(
    const bf16* __restrict__ qkv, const bf16* __restrict__ Vt,
    bf16* __restrict__ ctx) {
  const int bid = blockIdx.x;
  const int qt = bid >> 5;         // 0..15, 128-row q tiles
  const int bh = bid & 31;         // bid%8 == h -> XCD pinning per head
  const int h = bh & 7;
  const int b = bh >> 3;
  const int q0 = qt * 128;
  const int tid = threadIdx.x, lane = tid & 63, wv = tid >> 6;  // wv 0..7
  const int fr = lane & 15, fq = lane >> 4;
  const int xsw = fr & 7;

  __shared__ alignas(16) bf16 sK[3][64 * 64];
  __shared__ alignas(16) bf16 sV[3][64 * 64];

  const int srow = lane >> 3;                // 0..7 within 8-row issue
  const int scol = ((lane & 7) ^ srow) * 8;  // swizzled chunk (elements)

  // staging: each wave owns 8 K-rows and 8 V-rows per tile
  const bf16* gK = qkv + (size_t)(b * Sz + wv * 8 + srow) * 1536 + 512 + h * 64 + scol;
  const bf16* gV = Vt + (size_t)((b * 8 + h) * 64 + wv * 8 + srow) * Sz + scol;

  auto stage = [&](int buf, int t) {
    const size_t t0 = (size_t)t * 64;
    load_lds16(sK[buf] + (wv * 8) * 64, gK + t0 * 1536);
    load_lds16(sV[buf] + (wv * 8) * 64, gV + t0);
  };

  // ---- Q fragments direct global->VGPR (true cols, no swizzle needed)
  const bf16* gQf = qkv + (size_t)(b * Sz + q0 + wv * 16 + fr) * 1536 + h * 64;
  bf16x8 qb[2];
  qb[0] = *(const bf16x8*)(gQf + fq * 8);
  qb[1] = *(const bf16x8*)(gQf + (fq + 4) * 8);

  stage(0, 0);
  stage(1, 1);
  stage(2, 2);
  asm volatile("s_waitcnt vmcnt(2)" ::: "memory");  // qb + stage0/1 landed
  __builtin_amdgcn_s_barrier();                     // tile 0/1 ready everywhere
  asm volatile("" ::: "memory");

  const int colc0 = (fq ^ xsw) * 8;
  const int colc1 = ((fq + 4) ^ xsw) * 8;
  int qsrc[4];
#pragma unroll
  for (int r = 0; r < 4; ++r) qsrc[r] = (fq * 4 + r) | (lane & 48);

  float l_part = 0.f;
  f32x4 acc_o[4] = {};
  int cur = 0;

  for (int t = 0; t < 32; ++t) {
    // stage tile t+2 into the buffer freed after iter t-1's barrier
    if (t >= 1 && t + 2 < 32) {
      int nb = cur + 2;
      if (nb >= 3) nb -= 3;
      stage(nb, t + 2);
    }

    // S^T = K Q^T : lane holds q=fr, t'=fq*4+r+16j
    bf16x8 kf[2][4];
#pragma unroll
    for (int j = 0; j < 4; ++j) {
      kf[0][j] = *(const bf16x8*)(sK[cur] + (j * 16 + fr) * 64 + colc0);
      kf[1][j] = *(const bf16x8*)(sK[cur] + (j * 16 + fr) * 64 + colc1);
    }
    f32x4 sc[4];
    __builtin_amdgcn_s_setprio(1);
#pragma unroll
    for (int j = 0; j < 4; ++j) {
      f32x4 z = {0.f, 0.f, 0.f, 0.f};
      z = __builtin_amdgcn_mfma_f32_16x16x32_bf16(kf[0][j], qb[0], z, 0, 0, 0);
      sc[j] = __builtin_amdgcn_mfma_f32_16x16x32_bf16(kf[1][j], qb[1], z, 0, 0, 0);
    }
    __builtin_amdgcn_s_setprio(0);

    // max-free softmax: e = exp2(sc); pack to bf16 pairs
    unsigned c0[4], c1[4];
    float rs = 0.f;
#pragma unroll
    for (int j = 0; j < 4; ++j) {
      float e0 = __builtin_amdgcn_exp2f(sc[j][0]);
      float e1 = __builtin_amdgcn_exp2f(sc[j][1]);
      float e2 = __builtin_amdgcn_exp2f(sc[j][2]);
      float e3 = __builtin_amdgcn_exp2f(sc[j][3]);
      rs += (e0 + e1) + (e2 + e3);
      union { bf16 hh[2]; unsigned u; } pka, pkb;
      pka.hh[0] = (bf16)e0; pka.hh[1] = (bf16)e1;  // fuses to v_cvt_pk_bf16_f32
      pkb.hh[0] = (bf16)e2; pkb.hh[1] = (bf16)e3;
      c0[j] = pka.u;
      c1[j] = pkb.u;
    }
    l_part += rs;

    // in-register P redistribution to PV A-frag layout (verified R1-R3)
    bf16x8 pa[2];
#pragma unroll
    for (int kk = 0; kk < 2; ++kk) {
      unsigned x0 = c0[2 * kk], y0 = c0[2 * kk + 1];
      permswap32(x0, y0);
      permswap16(x0, y0);
      unsigned x1 = c1[2 * kk], y1 = c1[2 * kk + 1];
      permswap32(x1, y1);
      permswap16(x1, y1);
      union { unsigned u[4]; bf16x8 v; } pk;
      pk.u[0] = x0; pk.u[1] = x1; pk.u[2] = y0; pk.u[3] = y1;
      pa[kk] = pk.v;
    }

    // O += P V
    bf16x8 vf[2][4];
#pragma unroll
    for (int j = 0; j < 4; ++j) {
      vf[0][j] = *(const bf16x8*)(sV[cur] + (j * 16 + fr) * 64 + colc0);
      vf[1][j] = *(const bf16x8*)(sV[cur] + (j * 16 + fr) * 64 + colc1);
    }
    __builtin_amdgcn_s_setprio(1);
#pragma unroll
    for (int kk = 0; kk < 2; ++kk)
#pragma unroll
      for (int j = 0; j < 4; ++j)
        acc_o[j] = __builtin_amdgcn_mfma_f32_16x16x32_bf16(pa[kk], vf[kk][j], acc_o[j], 0, 0, 0);
    __builtin_amdgcn_s_setprio(0);

    // counted sync: own stage(t+1) landed (stage(t+2) stays in flight)
    if (t < 31) {
      if (t <= 29) asm volatile("s_waitcnt vmcnt(2)" ::: "memory");
      else         asm volatile("s_waitcnt vmcnt(0)" ::: "memory");
      __builtin_amdgcn_s_barrier();
      asm volatile("" ::: "memory");
    }
    cur = cur == 2 ? 0 : cur + 1;
  }

  float l = l_part;
  l += __shfl_xor(l, 16, 64);
  l += __shfl_xor(l, 32, 64);
  float rl[4];
#pragma unroll
  for (int r = 0; r < 4; ++r) rl[r] = 1.0f / __shfl(l, qsrc[r], 64);
#pragma unroll
  for (int j = 0; j < 4; ++j)
#pragma unroll
    for (int r = 0; r < 4; ++r) {
      const int row = b * Sz + q0 + wv * 16 + fq * 4 + r;
      const int col = h * 64 + j * 16 + fr;
      ctx[(size_t)row * Dz + col] = (bf16)(acc_o[j][r] * rl[r]);
    }
}

// =====================================================================
// LayerNorm: one wave per row of 512. bf16 input; fp32 or bf16 output.
// =====================================================================
template <int OUT_F32>
__global__ __launch_bounds__(256) void layer_norm_k(
    const bf16* __restrict__ y, const float* __restrict__ g,
    const float* __restrict__ be, void* __restrict__ out) {
  const int row = blockIdx.x * 4 + (threadIdx.x >> 6);
  const int lane = threadIdx.x & 63;
  const int col = lane * 8;
  bf16x8 hv = *(const bf16x8*)(y + (size_t)row * Dz + col);
  float v[8];
  float s = 0.f, ss = 0.f;
#pragma unroll
  for (int i = 0; i < 8; ++i) {
    v[i] = (float)hv[i];
    s += v[i];
    ss += v[i] * v[i];
  }
#pragma unroll
  for (int o = 1; o < 64; o <<= 1) {
    s += __shfl_xor(s, o, 64);
    ss += __shfl_xor(ss, o, 64);
  }
  const float mu = s * (1.0f / Dz);
  const float rstd = rsqrtf(ss * (1.0f / Dz) - mu * mu + EPSf);
  const float4* g4 = (const float4*)(g + col);
  const float4* b4 = (const float4*)(be + col);
  float4 ga = g4[0], gb = g4[1], ba = b4[0], bb = b4[1];
  float o8[8];
  o8[0] = (v[0] - mu) * rstd * ga.x + ba.x;
  o8[1] = (v[1] - mu) * rstd * ga.y + ba.y;
  o8[2] = (v[2] - mu) * rstd * ga.z + ba.z;
  o8[3] = (v[3] - mu) * rstd * ga.w + ba.w;
  o8[4] = (v[4] - mu) * rstd * gb.x + bb.x;
  o8[5] = (v[5] - mu) * rstd * gb.y + bb.y;
  o8[6] = (v[6] - mu) * rstd * gb.z + bb.z;
  o8[7] = (v[7] - mu) * rstd * gb.w + bb.w;
  if (OUT_F32) {
    float4* of = (float4*)((float*)out + (size_t)row * Dz + col);
    of[0] = make_float4(o8[0], o8[1], o8[2], o8[3]);
    of[1] = make_float4(o8[4], o8[5], o8[6], o8[7]);
  } else {
    bf16 ob[8];
#pragma unroll
    for (int i = 0; i < 8; ++i) ob[i] = (bf16)o8[i];
    *(uint4*)((bf16*)out + (size_t)row * Dz + col) = *(const uint4*)ob;
  }
}

// =====================================================================
// Fused prep: all 6 weight transposes (fp32[K,N] -> bf16[N,K], 64x64
// tiles), bias concat, x -> bf16 cast. One launch.
// =====================================================================
__global__ __launch_bounds__(256) void prep_all(
    const float* __restrict__ Wq, const float* __restrict__ Wk,
    const float* __restrict__ Wv, const float* __restrict__ Wo,
    const float* __restrict__ W1, const float* __restrict__ W2,
    const float* __restrict__ bq, const float* __restrict__ bk,
    const float* __restrict__ bv, const float* __restrict__ x,
    bf16* __restrict__ WqkvT, bf16* __restrict__ WoT,
    bf16* __restrict__ W1T, bf16* __restrict__ W2T,
    float* __restrict__ bqkv, bf16* __restrict__ xb) {
  __shared__ float tile[64][65];
  const int blk = blockIdx.x;
  const int t = threadIdx.x;
  if (blk < 768) {
    const float* W;
    bf16* Wt;
    int K, N, local;
    if (blk < 64)       { W = Wq; Wt = WqkvT;                       K = 512;  N = 512;  local = blk; }
    else if (blk < 128) { W = Wk; Wt = WqkvT + (size_t)512 * 512;   K = 512;  N = 512;  local = blk - 64; }
    else if (blk < 192) { W = Wv; Wt = WqkvT + (size_t)1024 * 512;  K = 512;  N = 512;  local = blk - 128; }
    else if (blk < 256) { W = Wo; Wt = WoT;                         K = 512;  N = 512;  local = blk - 192; }
    else if (blk < 512) { W = W1; Wt = W1T;                         K = 512;  N = 2048; local = blk - 256; }
    else                { W = W2; Wt = W2T;                         K = 2048; N = 512;  local = blk - 512; }
    const int kt = K / 64;
    const int k0 = (local % kt) * 64, n0 = (local / kt) * 64;
    const int r = t >> 2, c = (t & 3) * 16;
    const float* src = W + (size_t)(k0 + r) * N + n0 + c;
#pragma unroll
    for (int i = 0; i < 4; ++i) {
      float4 v = ((const float4*)src)[i];
      tile[r][c + i * 4 + 0] = v.x;
      tile[r][c + i * 4 + 1] = v.y;
      tile[r][c + i * 4 + 2] = v.z;
      tile[r][c + i * 4 + 3] = v.w;
    }
    __syncthreads();
    union { bf16 hh[16]; uint4 u[2]; } pk;
#pragma unroll
    for (int i = 0; i < 16; ++i) pk.hh[i] = (bf16)tile[c + i][r];
    uint4* dst = (uint4*)(Wt + (size_t)(n0 + r) * K + k0 + c);
    dst[0] = pk.u[0];
    dst[1] = pk.u[1];
  } else if (blk == 768) {
    for (int i = t; i < 1536; i += 256)
      bqkv[i] = i < 512 ? bq[i] : (i < 1024 ? bk[i - 512] : bv[i - 1024]);
  } else {
    const int local = blk - 769;  // 0..1023, each handles 1024 float4s
#pragma unroll
    for (int k = 0; k < 4; ++k) {
      const int i = local * 1024 + k * 256 + t;
      float4 v = ((const float4*)x)[i];
      bf16 tv[4] = {(bf16)v.x, (bf16)v.y, (bf16)v.z, (bf16)v.w};
      ((uint2*)xb)[i] = *(const uint2*)tv;
    }
  }
}

// =====================================================================
extern "C" void kernel_launch(void* const* d_in, const int* in_sizes, int n_in,
                              void* d_out, int out_size, void* d_ws, size_t ws_size,
                              hipStream_t stream) {
  const float* x   = (const float*)d_in[0];
  const float* Wq  = (const float*)d_in[1];
  const float* bq  = (const float*)d_in[2];
  const float* Wk  = (const float*)d_in[3];
  const float* bk  = (const float*)d_in[4];
  const float* Wv  = (const float*)d_in[5];
  const float* bvp = (const float*)d_in[6];
  const float* Wo  = (const float*)d_in[7];
  const float* bo  = (const float*)d_in[8];
  const float* W1  = (const float*)d_in[9];
  const float* b1  = (const float*)d_in[10];
  const float* W2  = (const float*)d_in[11];
  const float* b2  = (const float*)d_in[12];
  const float* g1  = (const float*)d_in[13];
  const float* be1 = (const float*)d_in[14];
  const float* g2  = (const float*)d_in[15];
  const float* be2 = (const float*)d_in[16];

  char* ws = (char*)d_ws;
  size_t off = 0;
  auto alloc = [&](size_t bytes) -> void* {
    void* p = ws + off;
    off += (bytes + 255) & ~(size_t)255;
    return p;
  };
  bf16*  WqkvT = (bf16*)alloc((size_t)1536 * 512 * 2);
  float* bqkv  = (float*)alloc(1536 * 4);
  bf16*  WoT   = (bf16*)alloc((size_t)512 * 512 * 2);
  bf16*  W1T   = (bf16*)alloc((size_t)2048 * 512 * 2);
  bf16*  W2T   = (bf16*)alloc((size_t)512 * 2048 * 2);
  bf16*  xb    = (bf16*)alloc((size_t)ROWSz * 512 * 2);
  bf16*  qkv   = (bf16*)alloc((size_t)ROWSz * 1536 * 2);    // 24 MB (Q,K rows)
  bf16*  Vt    = (bf16*)alloc((size_t)32 * 64 * 2048 * 2);  // 8 MB, written by QKV epilogue
  bf16*  ctx   = (bf16*)alloc((size_t)ROWSz * 512 * 2);
  bf16*  y1    = (bf16*)alloc((size_t)ROWSz * 512 * 2);     // Wo+resid out (bf16)
  bf16*  x1b   = (bf16*)alloc((size_t)ROWSz * 512 * 2);     // LN1 out
  bf16*  hbuf  = qkv;  // 32 MB alias over qkv+Vt (dead after attention+Wo)
  bf16*  y2    = y1;   // dead after LN1

  // fused prep (weights, bias concat, x cast)
  prep_all<<<dim3(1793), 256, 0, stream>>>(Wq, Wk, Wv, Wo, W1, W2, bq, bk, bvp, x,
                                           WqkvT, WoT, W1T, W2T, bqkv, xb);

  // QKV projection (fused N=1536; Q cols pre-scaled by C2; V cols -> Vt transposed)
  gemm_bt<128, 32, 3><<<dim3(12, 64), 256, 0, stream>>>(xb, WqkvT, bqkv, nullptr, nullptr, Vt, qkv, ROWSz, 1536, 512);
  // attention (512 blocks x 8 waves, 128 q-rows/block, head-pinned XCD map)
  flash_attn<<<dim3(512), 512, 0, stream>>>(qkv, Vt, ctx);
  // Wo + bias + residual(xb bf16) -> y1 bf16
  gemm_bt<64, 64, 4><<<dim3(4, 128), 256, 0, stream>>>(ctx, WoT, bo, nullptr, xb, nullptr, y1, ROWSz, 512, 512);
  layer_norm_k<0><<<dim3(2048), 256, 0, stream>>>(y1, g1, be1, x1b);
  // FFN
  gemm_bt<128, 32, 2><<<dim3(16, 64), 256, 0, stream>>>(x1b, W1T, b1, nullptr, nullptr, nullptr, hbuf, ROWSz, 2048, 512);
  gemm_bt<64, 64, 4><<<dim3(4, 128), 256, 0, stream>>>(hbuf, W2T, b2, nullptr, x1b, nullptr, y2, ROWSz, 512, 2048);
  layer_norm_k<1><<<dim3(2048), 256, 0, stream>>>(y2, g2, be2, d_out);
}

// Round 6
// 242.506 us; speedup vs baseline: 1.0137x; 1.0080x over previous
//
#include <hip/hip_runtime.h>
#include <hip/hip_bf16.h>
#include <stdint.h>

typedef __bf16 bf16;
typedef __attribute__((ext_vector_type(8))) __bf16 bf16x8;
typedef __attribute__((ext_vector_type(4))) float f32x4;

#define DEVI __device__ __forceinline__

constexpr int Bz = 4, Sz = 2048, Dz = 512, Hz = 8, DKz = 64, DFFz = 2048;
constexpr int ROWSz = Bz * Sz;  // 8192
constexpr float EPSf = 1e-5f;
constexpr float C2f = 0.125f * 1.44269504088896f;  // 1/sqrt(DK) * log2(e)

// ---- async global->LDS, 16B per lane. LDS dest is wave-uniform base + lane*16.
DEVI void load_lds16(void* lds, const void* g) {
  __builtin_amdgcn_global_load_lds(
      (const __attribute__((address_space(1))) void*)(uintptr_t)(g),
      (__attribute__((address_space(3))) void*)(uint32_t)(uintptr_t)(lds),
      16, 0, 0);
}

// gfx950 cross-lane half-swaps (pure VALU; all lanes active in this kernel).
DEVI void permswap32(unsigned& x, unsigned& y) {
  asm("v_permlane32_swap_b32 %0, %1" : "+v"(x), "+v"(y));
}
DEVI void permswap16(unsigned& x, unsigned& y) {
  asm("v_permlane16_swap_b32 %0, %1" : "+v"(x), "+v"(y));
}

// =====================================================================
// GEMM (best measured mix, R11/R14):  C = A[M,K] @ Bt[N,K]^T  +bias.
// =====================================================================
template <int BM, int BK, int EPI>
__global__ __launch_bounds__(256, BM == 128 ? 4 : 3) void gemm_bt(
    const bf16* __restrict__ A, const bf16* __restrict__ Bt,
    const float* __restrict__ bias, const float* __restrict__ resid,
    const bf16* __restrict__ residb, bf16* __restrict__ aux,
    void* __restrict__ Cout, int M, int N, int K) {
  constexpr int BN = 128;
  constexpr int MI = BM / 32;          // m-frags per wave
  constexpr int RPI = 512 / BK;        // rows per 16B-issue (16 @BK32, 8 @BK64)
  constexpr int AISS = (BM / 4) / RPI; // A issues per wave
  constexpr int BISS = 32 / RPI;       // B issues per wave
  __shared__ alignas(16) bf16 sA[2][BM * BK];
  __shared__ alignas(16) bf16 sB[2][BN * BK];
  const int tid = threadIdx.x;
  const int lane = tid & 63;
  const int wv = tid >> 6;
  const int n0 = blockIdx.x * BN;
  const int m0 = blockIdx.y * BM;

  const int srow = (BK == 32) ? (lane >> 2) : (lane >> 3);
  const int sch = (BK == 32) ? (((lane & 3) ^ (srow & 3)) * 8)
                             : (((lane & 7) ^ (srow & 7)) * 8);
  const bf16* gA = A + (size_t)(m0 + wv * (BM / 4) + srow) * K + sch;
  const bf16* gB = Bt + (size_t)(n0 + wv * 32 + srow) * K + sch;

  const int wm = (wv >> 1) * (BM / 2);
  const int wn = (wv & 1) * 64;
  const int fr = lane & 15;
  const int fq = lane >> 4;

  auto stage = [&](int buf, int k0) {
#pragma unroll
    for (int j = 0; j < AISS; ++j)
      load_lds16(sA[buf] + (wv * (BM / 4) + j * RPI) * BK, gA + (size_t)(j * RPI) * K + k0);
#pragma unroll
    for (int j = 0; j < BISS; ++j)
      load_lds16(sB[buf] + (wv * 32 + j * RPI) * BK, gB + (size_t)(j * RPI) * K + k0);
  };

  f32x4 acc[MI][4] = {};

  stage(0, 0);
  __syncthreads();  // barrier's vmcnt(0) drain completes tile 0

  const int niter = K / BK;
  for (int it = 0; it < niter; ++it) {
    const int cur = it & 1;
    if (it + 1 < niter) stage(cur ^ 1, (it + 1) * BK);
#pragma unroll
    for (int kk = 0; kk < BK / 32; ++kk) {
      const int fc = (BK == 32) ? ((fq ^ (fr & 3)) * 8)
                                : (((4 * kk + fq) ^ (fr & 7)) * 8);
      bf16x8 af[MI], bfr[4];
#pragma unroll
      for (int i = 0; i < MI; ++i)
        af[i] = *(const bf16x8*)(sA[cur] + (wm + i * 16 + fr) * BK + fc);
#pragma unroll
      for (int j = 0; j < 4; ++j)
        bfr[j] = *(const bf16x8*)(sB[cur] + (wn + j * 16 + fr) * BK + fc);
#pragma unroll
      for (int i = 0; i < MI; ++i)
#pragma unroll
        for (int j = 0; j < 4; ++j)
          acc[i][j] = __builtin_amdgcn_mfma_f32_16x16x32_bf16(af[i], bfr[j], acc[i][j], 0, 0, 0);
    }
    __syncthreads();  // readers done with cur + prefetch DMA drained
  }

#pragma unroll
  for (int i = 0; i < MI; ++i) {
#pragma unroll
    for (int j = 0; j < 4; ++j) {
      const int col = n0 + wn + j * 16 + fr;
      const float bv = bias[col];
      if (EPI == 3 && col >= 1024) {
        const int row0 = m0 + wm + i * 16 + fq * 4;
        const int hh = (col - 1024) >> 6, dk = (col - 1024) & 63;
        const int bb = row0 >> 11, s0 = row0 & 2047;
        bf16 pv[4];
#pragma unroll
        for (int r = 0; r < 4; ++r) pv[r] = (bf16)(acc[i][j][r] + bv);
        *(uint2*)(aux + (size_t)((bb * 8 + hh) * 64 + dk) * 2048 + s0) = *(const uint2*)pv;
      } else {
#pragma unroll
        for (int r = 0; r < 4; ++r) {
          const int row = m0 + wm + i * 16 + fq * 4 + r;
          const size_t idx = (size_t)row * N + col;
          float v = acc[i][j][r] + bv;
          if (EPI == 1) {
            ((bf16*)Cout)[idx] = (bf16)(v + resid[idx]);
          } else if (EPI == 2) {
            ((bf16*)Cout)[idx] = (bf16)(v > 0.f ? v : 0.f);
          } else if (EPI == 3) {
            ((bf16*)Cout)[idx] = (bf16)(col < 512 ? v * C2f : v);
          } else {
            ((bf16*)Cout)[idx] = (bf16)(v + (float)residb[idx]);
          }
        }
      }
    }
  }
}

// =====================================================================
// Flash attention v6 (R6): static pair schedule.
// R5 post-mortem: VGPR=48 (compiler register-starved; recomputing LDS
// addrs + 16 zero-movs/iter) and 32 wait+barrier cycles of stall.
// Fix: 4 LDS buffers (64KB, free at 2 blocks/CU), 2 tiles per barrier
// interval (16 barriers), stages issued at pair start complete under
// ~2 tiles of compute so pair-end vmcnt(0) is cheap; tiles unrolled x4
// so ALL buffer indices are compile-time (addresses hoisted, no cur
// arithmetic); hoisted ZERO f32x4 kills per-iter acc-init movs.
// Safety: buffers written at pair start were last read in the previous
// pair, behind that pair's end barrier; vmcnt(0)+barrier covers all
// cross-wave DMA visibility. 8 waves x 16 q-rows, head-pinned XCD map.
// =====================================================================
__global__ __launch_bounds__(512, 4) void flash_attn(
    const bf16* __restrict__ qkv, const bf16* __restrict__ Vt,
    bf16* __restrict__ ctx) {
  const int bid = blockIdx.x;
  const int qt = bid >> 5;         // 0..15, 128-row q tiles
  const int bh = bid & 31;         // bid%8 == h -> XCD pinning per head
  const int h = bh & 7;
  const int b = bh >> 3;
  const int q0 = qt * 128;
  const int tid = threadIdx.x, lane = tid & 63, wv = tid >> 6;  // wv 0..7
  const int fr = lane & 15, fq = lane >> 4;
  const int xsw = fr & 7;

  __shared__ alignas(16) bf16 sK[4][64 * 64];
  __shared__ alignas(16) bf16 sV[4][64 * 64];

  const int srow = lane >> 3;                // 0..7 within 8-row issue
  const int scol = ((lane & 7) ^ srow) * 8;  // swizzled chunk (elements)

  // staging: each wave owns 8 K-rows and 8 V-rows per tile
  const bf16* gK = qkv + (size_t)(b * Sz + wv * 8 + srow) * 1536 + 512 + h * 64 + scol;
  const bf16* gV = Vt + (size_t)((b * 8 + h) * 64 + wv * 8 + srow) * Sz + scol;

  auto stage = [&](int buf, int t) {
    const size_t t0 = (size_t)t * 64;
    load_lds16(sK[buf] + (wv * 8) * 64, gK + t0 * 1536);
    load_lds16(sV[buf] + (wv * 8) * 64, gV + t0);
  };

  // ---- Q fragments direct global->VGPR (true cols, no swizzle needed)
  const bf16* gQf = qkv + (size_t)(b * Sz + q0 + wv * 16 + fr) * 1536 + h * 64;
  bf16x8 qb[2];
  qb[0] = *(const bf16x8*)(gQf + fq * 8);
  qb[1] = *(const bf16x8*)(gQf + (fq + 4) * 8);

  stage(0, 0);
  stage(1, 1);
  asm volatile("s_waitcnt vmcnt(0)" ::: "memory");  // qb + tiles 0,1 landed
  __builtin_amdgcn_s_barrier();
  asm volatile("" ::: "memory");

  const int colc0 = (fq ^ xsw) * 8;
  const int colc1 = ((fq + 4) ^ xsw) * 8;
  int qsrc[4];
#pragma unroll
  for (int r = 0; r < 4; ++r) qsrc[r] = (fq * 4 + r) | (lane & 48);

  const f32x4 ZERO = {0.f, 0.f, 0.f, 0.f};
  float l_part = 0.f;
  f32x4 acc_o[4] = {};

  // ---- one K/V tile: QKT -> max-free softmax -> in-reg P redist -> PV
  auto tilebody = [&](const bf16* kb, const bf16* vb) {
    bf16x8 kf[2][4];
#pragma unroll
    for (int j = 0; j < 4; ++j) {
      kf[0][j] = *(const bf16x8*)(kb + (j * 16 + fr) * 64 + colc0);
      kf[1][j] = *(const bf16x8*)(kb + (j * 16 + fr) * 64 + colc1);
    }
    f32x4 sc[4];
    __builtin_amdgcn_s_setprio(1);
#pragma unroll
    for (int j = 0; j < 4; ++j) {
      f32x4 z = __builtin_amdgcn_mfma_f32_16x16x32_bf16(kf[0][j], qb[0], ZERO, 0, 0, 0);
      sc[j] = __builtin_amdgcn_mfma_f32_16x16x32_bf16(kf[1][j], qb[1], z, 0, 0, 0);
    }
    __builtin_amdgcn_s_setprio(0);

    unsigned c0[4], c1[4];
    float rs = 0.f;
#pragma unroll
    for (int j = 0; j < 4; ++j) {
      float e0 = __builtin_amdgcn_exp2f(sc[j][0]);
      float e1 = __builtin_amdgcn_exp2f(sc[j][1]);
      float e2 = __builtin_amdgcn_exp2f(sc[j][2]);
      float e3 = __builtin_amdgcn_exp2f(sc[j][3]);
      rs += (e0 + e1) + (e2 + e3);
      union { bf16 hh[2]; unsigned u; } pka, pkb;
      pka.hh[0] = (bf16)e0; pka.hh[1] = (bf16)e1;  // fuses to v_cvt_pk_bf16_f32
      pkb.hh[0] = (bf16)e2; pkb.hh[1] = (bf16)e3;
      c0[j] = pka.u;
      c1[j] = pkb.u;
    }
    l_part += rs;

    bf16x8 pa[2];
#pragma unroll
    for (int kk = 0; kk < 2; ++kk) {
      unsigned x0 = c0[2 * kk], y0 = c0[2 * kk + 1];
      permswap32(x0, y0);
      permswap16(x0, y0);
      unsigned x1 = c1[2 * kk], y1 = c1[2 * kk + 1];
      permswap32(x1, y1);
      permswap16(x1, y1);
      union { unsigned u[4]; bf16x8 v; } pk;
      pk.u[0] = x0; pk.u[1] = x1; pk.u[2] = y0; pk.u[3] = y1;
      pa[kk] = pk.v;
    }

    bf16x8 vf[2][4];
#pragma unroll
    for (int j = 0; j < 4; ++j) {
      vf[0][j] = *(const bf16x8*)(vb + (j * 16 + fr) * 64 + colc0);
      vf[1][j] = *(const bf16x8*)(vb + (j * 16 + fr) * 64 + colc1);
    }
    __builtin_amdgcn_s_setprio(1);
#pragma unroll
    for (int kk = 0; kk < 2; ++kk)
#pragma unroll
      for (int j = 0; j < 4; ++j)
        acc_o[j] = __builtin_amdgcn_mfma_f32_16x16x32_bf16(pa[kk], vf[kk][j], acc_o[j], 0, 0, 0);
    __builtin_amdgcn_s_setprio(0);
  };

  // ---- pair: stage tiles tp+2,tp+3 (write bufs last read in PREVIOUS
  // pair, behind its barrier), compute tiles tp,tp+1, drain, barrier.
  auto pair = [&](int tp, int b0, int b1, int sb0, int sb1,
                  bool do_stage, bool do_sync) {
    if (do_stage) {
      stage(sb0, tp + 2);
      stage(sb1, tp + 3);
    }
    tilebody(sK[b0], sV[b0]);
    tilebody(sK[b1], sV[b1]);
    if (do_sync) {
      asm volatile("s_waitcnt vmcnt(0)" ::: "memory");
      __builtin_amdgcn_s_barrier();
      asm volatile("" ::: "memory");
    }
  };

  for (int tp4 = 0; tp4 < 28; tp4 += 4) {
    pair(tp4,     0, 1, 2, 3, true, true);
    pair(tp4 + 2, 2, 3, 0, 1, true, true);
  }
  pair(28, 0, 1, 2, 3, true, true);    // stages tiles 30,31
  pair(30, 2, 3, 0, 1, false, false);  // final pair, no sync

  float l = l_part;
  l += __shfl_xor(l, 16, 64);
  l += __shfl_xor(l, 32, 64);
  float rl[4];
#pragma unroll
  for (int r = 0; r < 4; ++r) rl[r] = 1.0f / __shfl(l, qsrc[r], 64);
#pragma unroll
  for (int j = 0; j < 4; ++j)
#pragma unroll
    for (int r = 0; r < 4; ++r) {
      const int row = b * Sz + q0 + wv * 16 + fq * 4 + r;
      const int col = h * 64 + j * 16 + fr;
      ctx[(size_t)row * Dz + col] = (bf16)(acc_o[j][r] * rl[r]);
    }
}

// =====================================================================
// LayerNorm: one wave per row of 512. bf16 input; fp32 or bf16 output.
// =====================================================================
template <int OUT_F32>
__global__ __launch_bounds__(256) void layer_norm_k(
    const bf16* __restrict__ y, const float* __restrict__ g,
    const float* __restrict__ be, void* __restrict__ out) {
  const int row = blockIdx.x * 4 + (threadIdx.x >> 6);
  const int lane = threadIdx.x & 63;
  const int col = lane * 8;
  bf16x8 hv = *(const bf16x8*)(y + (size_t)row * Dz + col);
  float v[8];
  float s = 0.f, ss = 0.f;
#pragma unroll
  for (int i = 0; i < 8; ++i) {
    v[i] = (float)hv[i];
    s += v[i];
    ss += v[i] * v[i];
  }
#pragma unroll
  for (int o = 1; o < 64; o <<= 1) {
    s += __shfl_xor(s, o, 64);
    ss += __shfl_xor(ss, o, 64);
  }
  const float mu = s * (1.0f / Dz);
  const float rstd = rsqrtf(ss * (1.0f / Dz) - mu * mu + EPSf);
  const float4* g4 = (const float4*)(g + col);
  const float4* b4 = (const float4*)(be + col);
  float4 ga = g4[0], gb = g4[1], ba = b4[0], bb = b4[1];
  float o8[8];
  o8[0] = (v[0] - mu) * rstd * ga.x + ba.x;
  o8[1] = (v[1] - mu) * rstd * ga.y + ba.y;
  o8[2] = (v[2] - mu) * rstd * ga.z + ba.z;
  o8[3] = (v[3] - mu) * rstd * ga.w + ba.w;
  o8[4] = (v[4] - mu) * rstd * gb.x + bb.x;
  o8[5] = (v[5] - mu) * rstd * gb.y + bb.y;
  o8[6] = (v[6] - mu) * rstd * gb.z + bb.z;
  o8[7] = (v[7] - mu) * rstd * gb.w + bb.w;
  if (OUT_F32) {
    float4* of = (float4*)((float*)out + (size_t)row * Dz + col);
    of[0] = make_float4(o8[0], o8[1], o8[2], o8[3]);
    of[1] = make_float4(o8[4], o8[5], o8[6], o8[7]);
  } else {
    bf16 ob[8];
#pragma unroll
    for (int i = 0; i < 8; ++i) ob[i] = (bf16)o8[i];
    *(uint4*)((bf16*)out + (size_t)row * Dz + col) = *(const uint4*)ob;
  }
}

// =====================================================================
// Fused prep: all 6 weight transposes (fp32[K,N] -> bf16[N,K], 64x64
// tiles), bias concat, x -> bf16 cast. One launch.
// =====================================================================
__global__ __launch_bounds__(256) void prep_all(
    const float* __restrict__ Wq, const float* __restrict__ Wk,
    const float* __restrict__ Wv, const float* __restrict__ Wo,
    const float* __restrict__ W1, const float* __restrict__ W2,
    const float* __restrict__ bq, const float* __restrict__ bk,
    const float* __restrict__ bv, const float* __restrict__ x,
    bf16* __restrict__ WqkvT, bf16* __restrict__ WoT,
    bf16* __restrict__ W1T, bf16* __restrict__ W2T,
    float* __restrict__ bqkv, bf16* __restrict__ xb) {
  __shared__ float tile[64][65];
  const int blk = blockIdx.x;
  const int t = threadIdx.x;
  if (blk < 768) {
    const float* W;
    bf16* Wt;
    int K, N, local;
    if (blk < 64)       { W = Wq; Wt = WqkvT;                       K = 512;  N = 512;  local = blk; }
    else if (blk < 128) { W = Wk; Wt = WqkvT + (size_t)512 * 512;   K = 512;  N = 512;  local = blk - 64; }
    else if (blk < 192) { W = Wv; Wt = WqkvT + (size_t)1024 * 512;  K = 512;  N = 512;  local = blk - 128; }
    else if (blk < 256) { W = Wo; Wt = WoT;                         K = 512;  N = 512;  local = blk - 192; }
    else if (blk < 512) { W = W1; Wt = W1T;                         K = 512;  N = 2048; local = blk - 256; }
    else                { W = W2; Wt = W2T;                         K = 2048; N = 512;  local = blk - 512; }
    const int kt = K / 64;
    const int k0 = (local % kt) * 64, n0 = (local / kt) * 64;
    const int r = t >> 2, c = (t & 3) * 16;
    const float* src = W + (size_t)(k0 + r) * N + n0 + c;
#pragma unroll
    for (int i = 0; i < 4; ++i) {
      float4 v = ((const float4*)src)[i];
      tile[r][c + i * 4 + 0] = v.x;
      tile[r][c + i * 4 + 1] = v.y;
      tile[r][c + i * 4 + 2] = v.z;
      tile[r][c + i * 4 + 3] = v.w;
    }
    __syncthreads();
    union { bf16 hh[16]; uint4 u[2]; } pk;
#pragma unroll
    for (int i = 0; i < 16; ++i) pk.hh[i] = (bf16)tile[c + i][r];
    uint4* dst = (uint4*)(Wt + (size_t)(n0 + r) * K + k0 + c);
    dst[0] = pk.u[0];
    dst[1] = pk.u[1];
  } else if (blk == 768) {
    for (int i = t; i < 1536; i += 256)
      bqkv[i] = i < 512 ? bq[i] : (i < 1024 ? bk[i - 512] : bv[i - 1024]);
  } else {
    const int local = blk - 769;  // 0..1023, each handles 1024 float4s
#pragma unroll
    for (int k = 0; k < 4; ++k) {
      const int i = local * 1024 + k * 256 + t;
      float4 v = ((const float4*)x)[i];
      bf16 tv[4] = {(bf16)v.x, (bf16)v.y, (bf16)v.z, (bf16)v.w};
      ((uint2*)xb)[i] = *(const uint2*)tv;
    }
  }
}

// =====================================================================
extern "C" void kernel_launch(void* const* d_in, const int* in_sizes, int n_in,
                              void* d_out, int out_size, void* d_ws, size_t ws_size,
                              hipStream_t stream) {
  const float* x   = (const float*)d_in[0];
  const float* Wq  = (const float*)d_in[1];
  const float* bq  = (const float*)d_in[2];
  const float* Wk  = (const float*)d_in[3];
  const float* bk  = (const float*)d_in[4];
  const float* Wv  = (const float*)d_in[5];
  const float* bvp = (const float*)d_in[6];
  const float* Wo  = (const float*)d_in[7];
  const float* bo  = (const float*)d_in[8];
  const float* W1  = (const float*)d_in[9];
  const float* b1  = (const float*)d_in[10];
  const float* W2  = (const float*)d_in[11];
  const float* b2  = (const float*)d_in[12];
  const float* g1  = (const float*)d_in[13];
  const float* be1 = (const float*)d_in[14];
  const float* g2  = (const float*)d_in[15];
  const float* be2 = (const float*)d_in[16];

  char* ws = (char*)d_ws;
  size_t off = 0;
  auto alloc = [&](size_t bytes) -> void* {
    void* p = ws + off;
    off += (bytes + 255) & ~(size_t)255;
    return p;
  };
  bf16*  WqkvT = (bf16*)alloc((size_t)1536 * 512 * 2);
  float* bqkv  = (float*)alloc(1536 * 4);
  bf16*  WoT   = (bf16*)alloc((size_t)512 * 512 * 2);
  bf16*  W1T   = (bf16*)alloc((size_t)2048 * 512 * 2);
  bf16*  W2T   = (bf16*)alloc((size_t)512 * 2048 * 2);
  bf16*  xb    = (bf16*)alloc((size_t)ROWSz * 512 * 2);
  bf16*  qkv   = (bf16*)alloc((size_t)ROWSz * 1536 * 2);    // 24 MB (Q,K rows)
  bf16*  Vt    = (bf16*)alloc((size_t)32 * 64 * 2048 * 2);  // 8 MB, written by QKV epilogue
  bf16*  ctx   = (bf16*)alloc((size_t)ROWSz * 512 * 2);
  bf16*  y1    = (bf16*)alloc((size_t)ROWSz * 512 * 2);     // Wo+resid out (bf16)
  bf16*  x1b   = (bf16*)alloc((size_t)ROWSz * 512 * 2);     // LN1 out
  bf16*  hbuf  = qkv;  // 32 MB alias over qkv+Vt (dead after attention+Wo)
  bf16*  y2    = y1;   // dead after LN1

  // fused prep (weights, bias concat, x cast)
  prep_all<<<dim3(1793), 256, 0, stream>>>(Wq, Wk, Wv, Wo, W1, W2, bq, bk, bvp, x,
                                           WqkvT, WoT, W1T, W2T, bqkv, xb);

  // QKV projection (fused N=1536; Q cols pre-scaled by C2; V cols -> Vt transposed)
  gemm_bt<128, 32, 3><<<dim3(12, 64), 256, 0, stream>>>(xb, WqkvT, bqkv, nullptr, nullptr, Vt, qkv, ROWSz, 1536, 512);
  // attention (512 blocks x 8 waves, 128 q-rows/block, head-pinned XCD map)
  flash_attn<<<dim3(512), 512, 0, stream>>>(qkv, Vt, ctx);
  // Wo + bias + residual(xb bf16) -> y1 bf16
  gemm_bt<64, 64, 4><<<dim3(4, 128), 256, 0, stream>>>(ctx, WoT, bo, nullptr, xb, nullptr, y1, ROWSz, 512, 512);
  layer_norm_k<0><<<dim3(2048), 256, 0, stream>>>(y1, g1, be1, x1b);
  // FFN
  gemm_bt<128, 32, 2><<<dim3(16, 64), 256, 0, stream>>>(x1b, W1T, b1, nullptr, nullptr, nullptr, hbuf, ROWSz, 2048, 512);
  gemm_bt<64, 64, 4><<<dim3(4, 128), 256, 0, stream>>>(hbuf, W2T, b2, nullptr, x1b, nullptr, y2, ROWSz, 512, 2048);
  layer_norm_k<1><<<dim3(2048), 256, 0, stream>>>(y2, g2, be2, d_out);
}